// Round 1
// baseline (1057.647 us; speedup 1.0000x reference)
//
#include <hip/hip_runtime.h>
#include <hip/hip_bf16.h>

// Segment-sum: out[v, :] = sum over rows r with idx[r]==v of H[r, :]
// H: [N=625000, D=128] f32, idx: [N] int32 (harness converts int64 -> int32),
// out: [V=50000, D=128] f32.
//
// Round 1 strategy: 32 lanes per row; each lane float4-loads 16B of the row
// (fully coalesced, 512B per row) and does 4 global atomicAdd f32 into the
// output bucket. Output is zeroed via hipMemsetAsync each call (graph-safe,
// deterministic across replays since harness does not re-poison).

__global__ void AggrSum_48464410968234_kernel(const float* __restrict__ H,
                                              const int* __restrict__ idx,
                                              float* __restrict__ out,
                                              int n) {
    const int gid   = blockIdx.x * blockDim.x + threadIdx.x;
    const int row   = gid >> 5;          // 32 lanes per row
    const int lane  = gid & 31;          // 0..31, covers 128 floats as float4
    if (row >= n) return;

    const int v = idx[row];

    const float4 val =
        reinterpret_cast<const float4*>(H + (size_t)row * 128)[lane];

    float* dst = out + (size_t)v * 128 + (size_t)lane * 4;
    atomicAdd(dst + 0, val.x);
    atomicAdd(dst + 1, val.y);
    atomicAdd(dst + 2, val.z);
    atomicAdd(dst + 3, val.w);
}

extern "C" void kernel_launch(void* const* d_in, const int* in_sizes, int n_in,
                              void* d_out, int out_size, void* d_ws, size_t ws_size,
                              hipStream_t stream) {
    const float* H   = (const float*)d_in[0];
    const int*   idx = (const int*)d_in[1];
    float*       out = (float*)d_out;

    const int n = in_sizes[1];           // 625000 rows

    // Zero the output accumulator (graph-capture-safe async memset).
    hipMemsetAsync(d_out, 0, (size_t)out_size * sizeof(float), stream);

    const int threads = 256;
    const int rows_per_block = threads / 32;                 // 8
    const int blocks = (n + rows_per_block - 1) / rows_per_block;

    AggrSum_48464410968234_kernel<<<blocks, threads, 0, stream>>>(H, idx, out, n);
}

// Round 2
// 201.512 us; speedup vs baseline: 5.2486x; 5.2486x over previous
//
#include <hip/hip_runtime.h>
#include <hip/hip_bf16.h>

// Segment-sum: out[v,:] = sum_{r: idx[r]==v} H[r,:]
// H: [N=625000, 128] f32, idx: [N] int32, out: [V=50000, 128] f32.
//
// Two-phase counting sort:
//  K1 histogram (int atomics, 625K ops)
//  K2 exclusive scan of counts -> offsets + cursor (single block, shfl scan)
//  K3 scatter row ids into bucket order (int atomics on cursors)
//  K4 one wave per bucket: gather rows (coalesced 512B), register-accumulate,
//     one coalesced float4 store per bucket. No float atomics anywhere.

#ifndef V_SEG
#define V_SEG 50000
#endif

__global__ void hist_kernel(const int* __restrict__ idx, int* __restrict__ counts, int n) {
    int i = blockIdx.x * blockDim.x + threadIdx.x;
    const int stride = gridDim.x * blockDim.x;
    for (; i < n; i += stride) atomicAdd(&counts[idx[i]], 1);
}

__global__ __launch_bounds__(1024) void scan_kernel(const int* __restrict__ counts,
                                                    int* __restrict__ offsets,
                                                    int* __restrict__ cursor, int V) {
    __shared__ int s_wtot[16];
    __shared__ int s_woff[16];
    __shared__ int s_total;
    const int t = threadIdx.x;
    const int lane = t & 63;
    const int w = t >> 6;
    int running = 0;
    for (int base = 0; base < V; base += 1024) {
        const int gi = base + t;
        const int x = (gi < V) ? counts[gi] : 0;
        // wave-level inclusive scan (no barriers)
        int incl = x;
        #pragma unroll
        for (int d = 1; d < 64; d <<= 1) {
            int y = __shfl_up(incl, d, 64);
            if (lane >= d) incl += y;
        }
        if (lane == 63) s_wtot[w] = incl;
        __syncthreads();
        if (w == 0 && lane < 16) {
            const int wt = s_wtot[lane];
            int winc = wt;
            #pragma unroll
            for (int d = 1; d < 16; d <<= 1) {
                int y = __shfl_up(winc, d, 16);
                if (lane >= d) winc += y;
            }
            s_woff[lane] = winc - wt;          // exclusive wave offset
            if (lane == 15) s_total = winc;    // chunk total
        }
        __syncthreads();
        if (gi < V) {
            const int off = running + s_woff[w] + incl - x;
            offsets[gi] = off;
            cursor[gi]  = off;
        }
        running += s_total;     // same value in every thread
        __syncthreads();        // protect s_* before next chunk
    }
    if (t == 0) offsets[V] = running;
}

__global__ void scatter_kernel(const int* __restrict__ idx, int* __restrict__ cursor,
                               int* __restrict__ rowids, int n) {
    int i = blockIdx.x * blockDim.x + threadIdx.x;
    const int stride = gridDim.x * blockDim.x;
    for (; i < n; i += stride) {
        const int v = idx[i];
        const int pos = atomicAdd(&cursor[v], 1);
        rowids[pos] = i;
    }
}

__global__ __launch_bounds__(256) void gather_kernel(const float* __restrict__ H,
                                                     const int* __restrict__ offsets,
                                                     const int* __restrict__ rowids,
                                                     float* __restrict__ out, int V) {
    const int wid = blockIdx.x * (blockDim.x >> 6) + (threadIdx.x >> 6);
    if (wid >= V) return;
    const int lane = threadIdx.x & 63;
    const int half = lane >> 5;       // 0: even rows, 1: odd rows
    const int l32  = lane & 31;       // float4 slot within the 128-col row
    const int start = offsets[wid];
    const int end   = offsets[wid + 1];
    float4 acc = make_float4(0.f, 0.f, 0.f, 0.f);
    for (int r = start + half; r < end; r += 2) {
        const int row = rowids[r];
        const float4 v = reinterpret_cast<const float4*>(H + (size_t)row * 128)[l32];
        acc.x += v.x; acc.y += v.y; acc.z += v.z; acc.w += v.w;
    }
    // combine the two 32-lane halves (same columns, different rows)
    acc.x += __shfl_xor(acc.x, 32, 64);
    acc.y += __shfl_xor(acc.y, 32, 64);
    acc.z += __shfl_xor(acc.z, 32, 64);
    acc.w += __shfl_xor(acc.w, 32, 64);
    if (half == 0)
        reinterpret_cast<float4*>(out + (size_t)wid * 128)[l32] = acc;
}

// ---- round-1 fallback (if ws too small): direct f32 atomics ----
__global__ void atomic_fallback_kernel(const float* __restrict__ H,
                                       const int* __restrict__ idx,
                                       float* __restrict__ out, int n) {
    const int gid  = blockIdx.x * blockDim.x + threadIdx.x;
    const int row  = gid >> 5;
    const int lane = gid & 31;
    if (row >= n) return;
    const int v = idx[row];
    const float4 val = reinterpret_cast<const float4*>(H + (size_t)row * 128)[lane];
    float* dst = out + (size_t)v * 128 + (size_t)lane * 4;
    atomicAdd(dst + 0, val.x);
    atomicAdd(dst + 1, val.y);
    atomicAdd(dst + 2, val.z);
    atomicAdd(dst + 3, val.w);
}

static inline size_t align_up(size_t x, size_t a) { return (x + a - 1) & ~(a - 1); }

extern "C" void kernel_launch(void* const* d_in, const int* in_sizes, int n_in,
                              void* d_out, int out_size, void* d_ws, size_t ws_size,
                              hipStream_t stream) {
    const float* H   = (const float*)d_in[0];
    const int*   idx = (const int*)d_in[1];
    float*       out = (float*)d_out;
    const int n = in_sizes[1];          // 625000 rows
    const int V = V_SEG;

    // ws layout
    size_t o = 0;
    const size_t counts_off  = o; o = align_up(o + (size_t)V * 4, 256);
    const size_t offsets_off = o; o = align_up(o + (size_t)(V + 1) * 4, 256);
    const size_t cursor_off  = o; o = align_up(o + (size_t)V * 4, 256);
    const size_t rowids_off  = o; o = align_up(o + (size_t)n * 4, 256);
    const size_t need = o;

    if (ws_size < need) {
        // fallback: direct atomics (round-1 path)
        hipMemsetAsync(d_out, 0, (size_t)out_size * sizeof(float), stream);
        const int threads = 256;
        const int blocks = (n * 32 + threads - 1) / threads;
        atomic_fallback_kernel<<<blocks, threads, 0, stream>>>(H, idx, out, n);
        return;
    }

    char* ws = (char*)d_ws;
    int* counts  = (int*)(ws + counts_off);
    int* offsets = (int*)(ws + offsets_off);
    int* cursor  = (int*)(ws + cursor_off);
    int* rowids  = (int*)(ws + rowids_off);

    hipMemsetAsync(counts, 0, (size_t)V * 4, stream);

    hist_kernel<<<2048, 256, 0, stream>>>(idx, counts, n);
    scan_kernel<<<1, 1024, 0, stream>>>(counts, offsets, cursor, V);
    scatter_kernel<<<2048, 256, 0, stream>>>(idx, cursor, rowids, n);

    const int waves_per_block = 256 / 64;                    // 4 buckets per block
    const int gblocks = (V + waves_per_block - 1) / waves_per_block;
    gather_kernel<<<gblocks, 256, 0, stream>>>(H, offsets, rowids, out, V);
}

// Round 3
// 121.317 us; speedup vs baseline: 8.7180x; 1.6610x over previous
//
#include <hip/hip_runtime.h>
#include <hip/hip_bf16.h>

// Segment-sum: out[v,:] = sum_{r: idx[r]==v} H[r,:]
// H: [N=625000, 128] f32, idx: [N] int32, out: [V=50000, 128] f32.
//
// Round 3: fixed-capacity binning (no histogram, no scan).
//  K1 scatter: pos = atomicAdd(&counts[v],1); rowids[v*CAP+pos] = row  (int atomics only)
//  K2 gather : one wave per bucket; coalesced per-lane rowid load + __shfl
//              broadcast; 32-lane float4 row gathers; register accumulate;
//              one coalesced 512B store per bucket (writes zeros for empty
//              buckets -> no d_out memset needed).
// Buckets are ~Poisson(12.5); P(count>64) ~ 1e-29. For full generality a
// bucket that overflows CAP falls back to a (slow, never-taken) full scan
// of idx inside the gather wave.

#ifndef V_SEG
#define V_SEG 50000
#endif
#define CAP 64

__global__ void scatter_kernel(const int* __restrict__ idx,
                               int* __restrict__ counts,
                               int* __restrict__ rowids, int n) {
    int i = blockIdx.x * blockDim.x + threadIdx.x;
    const int stride = gridDim.x * blockDim.x;
    for (; i < n; i += stride) {
        const int v = idx[i];
        const int pos = atomicAdd(&counts[v], 1);
        if (pos < CAP) rowids[v * CAP + pos] = i;
    }
}

__global__ __launch_bounds__(256) void gather_kernel(const float* __restrict__ H,
                                                     const int* __restrict__ counts,
                                                     const int* __restrict__ rowids,
                                                     const int* __restrict__ idx,
                                                     float* __restrict__ out,
                                                     int V, int n) {
    const int wid = blockIdx.x * (blockDim.x >> 6) + (threadIdx.x >> 6);
    if (wid >= V) return;
    const int lane = threadIdx.x & 63;
    const int half = lane >> 5;       // 0: even-numbered rows, 1: odd
    const int l32  = lane & 31;       // float4 slot within the 128-col row

    const int cnt = counts[wid];
    float4 acc = make_float4(0.f, 0.f, 0.f, 0.f);

    if (cnt <= CAP) {
        // One coalesced load: lane i holds candidate rowid i of this bucket.
        const int rid = rowids[wid * CAP + lane];   // always in-bounds; >cnt unused
        for (int r = half; r < cnt; r += 2) {
            const int row = __shfl(rid, r, 64);
            const float4 v = reinterpret_cast<const float4*>(H + (size_t)row * 128)[l32];
            acc.x += v.x; acc.y += v.y; acc.z += v.z; acc.w += v.w;
        }
    } else {
        // Overflow fallback: full scan (correct for any input; never taken
        // for Poisson(12.5) buckets).
        for (int r = half; r < n; r += 2) {
            if (idx[r] == wid) {
                const float4 v = reinterpret_cast<const float4*>(H + (size_t)r * 128)[l32];
                acc.x += v.x; acc.y += v.y; acc.z += v.z; acc.w += v.w;
            }
        }
    }

    // combine the two 32-lane halves (same columns, different rows)
    acc.x += __shfl_xor(acc.x, 32, 64);
    acc.y += __shfl_xor(acc.y, 32, 64);
    acc.z += __shfl_xor(acc.z, 32, 64);
    acc.w += __shfl_xor(acc.w, 32, 64);
    if (half == 0)
        reinterpret_cast<float4*>(out + (size_t)wid * 128)[l32] = acc;
}

// ---- fallback (if ws too small): direct f32 atomics ----
__global__ void atomic_fallback_kernel(const float* __restrict__ H,
                                       const int* __restrict__ idx,
                                       float* __restrict__ out, int n) {
    const int gid  = blockIdx.x * blockDim.x + threadIdx.x;
    const int row  = gid >> 5;
    const int lane = gid & 31;
    if (row >= n) return;
    const int v = idx[row];
    const float4 val = reinterpret_cast<const float4*>(H + (size_t)row * 128)[lane];
    float* dst = out + (size_t)v * 128 + (size_t)lane * 4;
    atomicAdd(dst + 0, val.x);
    atomicAdd(dst + 1, val.y);
    atomicAdd(dst + 2, val.z);
    atomicAdd(dst + 3, val.w);
}

static inline size_t align_up(size_t x, size_t a) { return (x + a - 1) & ~(a - 1); }

extern "C" void kernel_launch(void* const* d_in, const int* in_sizes, int n_in,
                              void* d_out, int out_size, void* d_ws, size_t ws_size,
                              hipStream_t stream) {
    const float* H   = (const float*)d_in[0];
    const int*   idx = (const int*)d_in[1];
    float*       out = (float*)d_out;
    const int n = in_sizes[1];          // 625000 rows
    const int V = V_SEG;

    // ws layout
    size_t o = 0;
    const size_t counts_off = o; o = align_up(o + (size_t)V * 4, 256);
    const size_t rowids_off = o; o = align_up(o + (size_t)V * CAP * 4, 256);
    const size_t need = o;

    if (ws_size < need) {
        hipMemsetAsync(d_out, 0, (size_t)out_size * sizeof(float), stream);
        const int threads = 256;
        const int blocks = (n * 32 + threads - 1) / threads;
        atomic_fallback_kernel<<<blocks, threads, 0, stream>>>(H, idx, out, n);
        return;
    }

    char* ws = (char*)d_ws;
    int* counts = (int*)(ws + counts_off);
    int* rowids = (int*)(ws + rowids_off);

    hipMemsetAsync(counts, 0, (size_t)V * 4, stream);

    scatter_kernel<<<1024, 256, 0, stream>>>(idx, counts, rowids, n);

    const int waves_per_block = 256 / 64;                    // 4 buckets per block
    const int gblocks = (V + waves_per_block - 1) / waves_per_block;
    gather_kernel<<<gblocks, 256, 0, stream>>>(H, counts, rowids, idx, out, V, n);
}

// Round 6
// 106.523 us; speedup vs baseline: 9.9288x; 1.1389x over previous
//
#include <hip/hip_runtime.h>
#include <hip/hip_bf16.h>

// Segment-sum: out[v,:] = sum_{r: idx[r]==v} H[r,:]
// H: [N=625000, 128] f32, idx: [N] int32, out: [V=50000, 128] f32.
//
// Round 6: fixed-capacity binning + branchless 4-deep gather.
//  K1 scatter: int4-vectorized; pos = atomicAdd(&counts[v],1); bin row id.
//  K2 gather : one wave per bucket. CRITICAL: every __shfl executes with all
//              64 lanes active (trip count is wave-uniform since cnt is
//              per-bucket); tail entries are handled by masking the
//              accumulate, NOT by divergent control flow. (Round-5 bug:
//              __shfl from inactive lanes returns garbage on CDNA.)
//              4 rows in flight per half-wave = 8 independent 512B loads
//              per wave. Nontemporal H loads + out store.

#ifndef V_SEG
#define V_SEG 50000
#endif
#define CAP 64

typedef float f4 __attribute__((ext_vector_type(4)));

__global__ void scatter_kernel(const int* __restrict__ idx,
                               int* __restrict__ counts,
                               int* __restrict__ rowids, int n) {
    const int n4 = n >> 2;                     // 625000 / 4 = 156250 exactly
    int i = blockIdx.x * blockDim.x + threadIdx.x;
    const int stride = gridDim.x * blockDim.x;
    const int4* __restrict__ idx4 = reinterpret_cast<const int4*>(idx);
    for (; i < n4; i += stride) {
        const int4 v = idx4[i];
        const int base = i << 2;
        int p;
        p = atomicAdd(&counts[v.x], 1); if (p < CAP) rowids[v.x * CAP + p] = base + 0;
        p = atomicAdd(&counts[v.y], 1); if (p < CAP) rowids[v.y * CAP + p] = base + 1;
        p = atomicAdd(&counts[v.z], 1); if (p < CAP) rowids[v.z * CAP + p] = base + 2;
        p = atomicAdd(&counts[v.w], 1); if (p < CAP) rowids[v.w * CAP + p] = base + 3;
    }
    // tail (n not multiple of 4)
    if (blockIdx.x == 0 && threadIdx.x < (n & 3)) {
        const int r = (n4 << 2) + threadIdx.x;
        const int v = idx[r];
        const int p = atomicAdd(&counts[v], 1);
        if (p < CAP) rowids[v * CAP + p] = r;
    }
}

__device__ __forceinline__ f4 nt_load_row(const float* H, int row, int l32) {
    return __builtin_nontemporal_load(
        reinterpret_cast<const f4*>(H + (size_t)row * 128) + l32);
}

__global__ __launch_bounds__(256) void gather_kernel(const float* __restrict__ H,
                                                     const int* __restrict__ counts,
                                                     const int* __restrict__ rowids,
                                                     const int* __restrict__ idx,
                                                     float* __restrict__ out,
                                                     int V, int n) {
    const int wid = blockIdx.x * (blockDim.x >> 6) + (threadIdx.x >> 6);
    if (wid >= V) return;
    const int lane = threadIdx.x & 63;
    const int half = lane >> 5;       // 0: even bucket entries, 1: odd
    const int l32  = lane & 31;       // float4 slot within the 128-col row

    const int cnt = counts[wid];      // wave-uniform
    f4 a0 = {0.f, 0.f, 0.f, 0.f};
    f4 a1 = {0.f, 0.f, 0.f, 0.f};
    f4 a2 = {0.f, 0.f, 0.f, 0.f};
    f4 a3 = {0.f, 0.f, 0.f, 0.f};

    if (cnt <= CAP) {
        // One coalesced load: lane i holds candidate rowid i of this bucket.
        const int rid = rowids[wid * CAP + lane];
        const int iters = (cnt + 7) >> 3;     // wave-uniform trip count
        int r = half;                         // entries r, r+2, r+4, r+6 per iter
        for (int t = 0; t < iters; ++t, r += 8) {
            const int r0 = r, r1 = r + 2, r2 = r + 4, r3 = r + 6;
            // Clamp shfl index to a valid entry; mask the accumulate instead
            // of branching, so all 64 lanes stay active for every __shfl.
            const int   i0 = (r0 < cnt) ? r0 : 0;
            const int   i1 = (r1 < cnt) ? r1 : 0;
            const int   i2 = (r2 < cnt) ? r2 : 0;
            const int   i3 = (r3 < cnt) ? r3 : 0;
            const float m0 = (r0 < cnt) ? 1.f : 0.f;
            const float m1 = (r1 < cnt) ? 1.f : 0.f;
            const float m2 = (r2 < cnt) ? 1.f : 0.f;
            const float m3 = (r3 < cnt) ? 1.f : 0.f;
            const int row0 = __shfl(rid, i0, 64);
            const int row1 = __shfl(rid, i1, 64);
            const int row2 = __shfl(rid, i2, 64);
            const int row3 = __shfl(rid, i3, 64);
            const f4 v0 = nt_load_row(H, row0, l32);
            const f4 v1 = nt_load_row(H, row1, l32);
            const f4 v2 = nt_load_row(H, row2, l32);
            const f4 v3 = nt_load_row(H, row3, l32);
            a0 += m0 * v0;
            a1 += m1 * v1;
            a2 += m2 * v2;
            a3 += m3 * v3;
        }
    } else {
        // Overflow fallback: full scan (correct for any input; effectively
        // never taken for Poisson(12.5) buckets). No cross-lane ops inside.
        for (int r = half; r < n; r += 2) {
            if (idx[r] == wid) {
                const f4 v = reinterpret_cast<const f4*>(H + (size_t)r * 128)[l32];
                a0 += v;
            }
        }
    }

    f4 acc = (a0 + a1) + (a2 + a3);

    // combine the two 32-lane halves (same columns, different row subsets)
    acc.x += __shfl_xor(acc.x, 32, 64);
    acc.y += __shfl_xor(acc.y, 32, 64);
    acc.z += __shfl_xor(acc.z, 32, 64);
    acc.w += __shfl_xor(acc.w, 32, 64);
    if (half == 0)
        __builtin_nontemporal_store(acc,
            reinterpret_cast<f4*>(out + (size_t)wid * 128) + l32);
}

// ---- fallback (if ws too small): direct f32 atomics ----
__global__ void atomic_fallback_kernel(const float* __restrict__ H,
                                       const int* __restrict__ idx,
                                       float* __restrict__ out, int n) {
    const int gid  = blockIdx.x * blockDim.x + threadIdx.x;
    const int row  = gid >> 5;
    const int lane = gid & 31;
    if (row >= n) return;
    const int v = idx[row];
    const float4 val = reinterpret_cast<const float4*>(H + (size_t)row * 128)[lane];
    float* dst = out + (size_t)v * 128 + (size_t)lane * 4;
    atomicAdd(dst + 0, val.x);
    atomicAdd(dst + 1, val.y);
    atomicAdd(dst + 2, val.z);
    atomicAdd(dst + 3, val.w);
}

static inline size_t align_up(size_t x, size_t a) { return (x + a - 1) & ~(a - 1); }

extern "C" void kernel_launch(void* const* d_in, const int* in_sizes, int n_in,
                              void* d_out, int out_size, void* d_ws, size_t ws_size,
                              hipStream_t stream) {
    const float* H   = (const float*)d_in[0];
    const int*   idx = (const int*)d_in[1];
    float*       out = (float*)d_out;
    const int n = in_sizes[1];          // 625000 rows
    const int V = V_SEG;

    // ws layout
    size_t o = 0;
    const size_t counts_off = o; o = align_up(o + (size_t)V * 4, 256);
    const size_t rowids_off = o; o = align_up(o + (size_t)V * CAP * 4, 256);
    const size_t need = o;

    if (ws_size < need) {
        (void)hipMemsetAsync(d_out, 0, (size_t)out_size * sizeof(float), stream);
        const int threads = 256;
        const int blocks = (n * 32 + threads - 1) / threads;
        atomic_fallback_kernel<<<blocks, threads, 0, stream>>>(H, idx, out, n);
        return;
    }

    char* ws = (char*)d_ws;
    int* counts = (int*)(ws + counts_off);
    int* rowids = (int*)(ws + rowids_off);

    (void)hipMemsetAsync(counts, 0, (size_t)V * 4, stream);

    scatter_kernel<<<1024, 256, 0, stream>>>(idx, counts, rowids, n);

    const int waves_per_block = 256 / 64;                    // 4 buckets per block
    const int gblocks = (V + waves_per_block - 1) / waves_per_block;
    gather_kernel<<<gblocks, 256, 0, stream>>>(H, counts, rowids, idx, out, V, n);
}